// Round 6
// baseline (249.166 us; speedup 1.0000x reference)
//
#include <hip/hip_runtime.h>
#include <hip/hip_bf16.h>
#include <stdint.h>

#define N_ROWS 8192
#define IN_DIM 4096
#define OUT_DIM 4096
#define EPS 1e-5f
#define QSCALE 16.0f
#define INV_QS 0.0625f

typedef __attribute__((ext_vector_type(4))) int i32x4;
typedef __attribute__((ext_vector_type(16))) char c8x16;
typedef __attribute__((ext_vector_type(8))) char c8x8;

typedef const __attribute__((address_space(1))) void gbl_void_t;
typedef __attribute__((address_space(3))) void lds_void_t;

__device__ __forceinline__ void gload_lds16(const void* g, void* l) {
    __builtin_amdgcn_global_load_lds((gbl_void_t*)g, (lds_void_t*)l, 16, 0, 0);
}

// ---------------- kernel 1: x_i8 = clamp(round(input * factor * 16), -127, 127) ----------------
__global__ __launch_bounds__(256) void scale_quant_kernel(
    const float* __restrict__ input, const float* __restrict__ factor,
    char* __restrict__ xq)
{
    long long idx = (long long)blockIdx.x * blockDim.x + threadIdx.x;
    long long base = idx * 16;
    if (base >= (long long)N_ROWS * IN_DIM) return;
    int col = (int)(base & (IN_DIM - 1));   // multiple of 16
    c8x16 r;
    #pragma unroll
    for (int q = 0; q < 4; ++q) {
        float4 a = *(const float4*)(input + base + q * 4);
        float4 f = *(const float4*)(factor + col + q * 4);
        float v[4] = {a.x*f.x, a.y*f.y, a.z*f.z, a.w*f.w};
        #pragma unroll
        for (int j = 0; j < 4; ++j) {
            int t = __float2int_rn(v[j] * QSCALE);
            t = t > 127 ? 127 : (t < -127 ? -127 : t);
            r[q * 4 + j] = (char)t;
        }
    }
    *(c8x16*)(xq + base) = r;
}

// ---------------- kernel 2: unpack packed ±1 weights to i8 ----------------
__global__ __launch_bounds__(256) void unpack_kernel(
    const int* __restrict__ wpacked, char* __restrict__ wq)
{
    int idx = blockIdx.x * blockDim.x + threadIdx.x;
    if (idx >= OUT_DIM * (IN_DIM / 8)) return;
    unsigned byte = (unsigned)wpacked[idx];
    c8x8 r;
    #pragma unroll
    for (int b = 0; b < 8; ++b)
        r[b] = (char)(1 - 2 * (int)((byte >> b) & 1u));   // bit0 -> +1, bit1 -> -1
    *(c8x8*)(wq + (long long)idx * 8) = r;
}

// ---------------- kernel 3: 128x128 8-phase i8 GEMM, 2 WGs/CU ----------------
// C[m][o] = (sum_k xq[m][k]*wq[o][k]) * wscale[o] / 16
// 256 thr = 4 waves (2M x 2N); wave tile 64x64; BK=128 i8; LDS 64KiB dbuf
// -> 2 independent workgroups co-resident per CU (phase overhead of one WG
// hides under the other's MFMA). Same replay-validated r5 protocol:
// stage cadence A1@P1,B0@P2,B1@P3,A0@P4 (mirrored), vmcnt(6) at P4/P8.

template<int M0, int KS>
__device__ __forceinline__ void read_a2(i32x4 (&f)[2], const char* ap, int lane) {
    int rb = (lane & 15) << 7, g = lane >> 4, x = lane & 7;
    #pragma unroll
    for (int m = 0; m < 2; ++m)
        f[m] = *(const i32x4*)(ap + (M0 + m) * 2048 + rb + (((KS * 4 + g) ^ x) << 4));
}
template<int KS>
__device__ __forceinline__ void read_b4(i32x4 (&f)[4], const char* bp, int lane) {
    int rb = (lane & 15) << 7, g = lane >> 4, x = lane & 7;
    #pragma unroll
    for (int n = 0; n < 4; ++n)
        f[n] = *(const i32x4*)(bp + n * 2048 + rb + (((KS * 4 + g) ^ x) << 4));
}
template<int MQ>   // 0: acc rows 0..1, 1: acc rows 2..3
__device__ __forceinline__ void mfma8(i32x4 (&acc)[4][4], i32x4 (&a2)[2], i32x4 (&b4)[4]) {
    #pragma unroll
    for (int i = 0; i < 2; ++i)
        #pragma unroll
        for (int j = 0; j < 4; ++j)
            acc[MQ * 2 + i][j] = __builtin_amdgcn_mfma_i32_16x16x64_i8(
                a2[i], b4[j], acc[MQ * 2 + i][j], 0, 0, 0);
}

__device__ __forceinline__ void stage_half(const char* g, char* l, int w) {
    // wave w (of 4) stages rows w*16..w*16+15 (2 x 8 rows x 128B) of a 64x128B half
    gload_lds16(g + (size_t)(w * 16)     * IN_DIM, l + w * 2048);
    gload_lds16(g + (size_t)(w * 16 + 8) * IN_DIM, l + w * 2048 + 1024);
}

#define SYNC_PRE() do { __builtin_amdgcn_s_barrier(); \
    asm volatile("s_waitcnt lgkmcnt(0)" ::: "memory"); \
    __builtin_amdgcn_sched_barrier(0); \
    __builtin_amdgcn_s_setprio(1); } while(0)
#define SYNC_POST() do { __builtin_amdgcn_s_setprio(0); \
    __builtin_amdgcn_s_barrier(); } while(0)
#define VMCNT(n) asm volatile("s_waitcnt vmcnt(" #n ")" ::: "memory")

__global__ __launch_bounds__(256, 2) void gemm_kernel(
    const char* __restrict__ A, const char* __restrict__ B,
    const float* __restrict__ wscale, float* __restrict__ C)
{
    __shared__ char ldsb[65536];   // 64 KiB

    int nwg = gridDim.x;   // 2048, divisible by 8
    int bid = blockIdx.x;
    int swz = (bid & 7) * (nwg >> 3) + (bid >> 3);   // bijective XCD swizzle
    int bn = swz & 31;     // 32 col panels
    int bm = swz >> 5;     // 64 row panels
    int m0 = bm * 128, n0 = bn * 128;

    int tid = threadIdx.x;
    int lane = tid & 63;
    int w = tid >> 6;            // wave 0..3
    int wm = w >> 1, wn = w & 1; // 2M x 2N

    // staging per-lane global base (inverse-swizzled source; swizzle key = row&7)
    int srow = lane >> 3, sslot = (lane & 7) ^ srow;
    const char* Ag = A + (size_t)(m0 + srow) * IN_DIM + sslot * 16;
    const char* Bg = B + (size_t)(n0 + srow) * IN_DIM + sslot * 16;
    const size_t H = (size_t)64 * IN_DIM;   // 64-row half-tile stride

    char* L = ldsb;
    // regions (bytes): buf0: A0=0 A1=8192 B0=16384 B1=24576; buf1: +32768
    const char* ap0 = ldsb + wm * 8192;            // wave's 64 A rows = one region
    const char* ap1 = ap0 + 32768;
    const char* bp0 = ldsb + 16384 + wn * 8192;    // wave's 64 B rows = one region
    const char* bp1 = bp0 + 32768;

    i32x4 afl[2], afh[2], bf0[4], bf1[4];
    i32x4 acc[4][4] = {};

    // prologue: T0 -> buf0 (B0,B1,A0,A1); T1 -> buf1 (B0,B1,A0); 14 loads/wave
    stage_half(Bg,           L + 16384, w);
    stage_half(Bg + H,       L + 24576, w);
    stage_half(Ag,           L + 0,     w);
    stage_half(Ag + H,       L + 8192,  w);
    stage_half(Bg + 128,     L + 49152, w);
    stage_half(Bg + H + 128, L + 57344, w);
    stage_half(Ag + 128,     L + 32768, w);
    VMCNT(6);                     // T0's 8 loads landed
    __builtin_amdgcn_s_barrier();

    for (int it = 0; it < 15; ++it) {
        size_t s1 = (size_t)(2 * it + 1) * 128;
        size_t s2 = (size_t)(2 * it + 2) * 128;
        size_t s3 = (size_t)(2 * it + 3) * 128;

        // ---- T0 (buf0) ----
        // P1: stage A1(T1)
        read_a2<0, 0>(afl, ap0, lane);
        read_b4<0>(bf0, bp0, lane);
        if (wm == 0) read_b4<1>(bf1, bp0, lane);
        stage_half(Ag + H + s1, L + 40960, w);
        SYNC_PRE(); mfma8<0>(acc, afl, bf0); SYNC_POST();
        // P2: stage B0(T2)
        read_a2<2, 0>(afh, ap0, lane);
        if (wm == 1) read_b4<1>(bf1, bp0, lane);
        stage_half(Bg + s2, L + 16384, w);
        SYNC_PRE(); mfma8<1>(acc, afh, bf0); SYNC_POST();
        // P3: stage B1(T2)
        read_a2<0, 1>(afl, ap0, lane);
        if (wn == 0) read_a2<2, 1>(afh, ap0, lane);
        stage_half(Bg + H + s2, L + 24576, w);
        SYNC_PRE(); mfma8<0>(acc, afl, bf1); SYNC_POST();
        // P4: stage A0(T2); counted vmcnt -> T1 fully landed
        if (wn == 1) read_a2<2, 1>(afh, ap0, lane);
        stage_half(Ag + s2, L + 0, w);
        VMCNT(6);
        SYNC_PRE(); mfma8<1>(acc, afh, bf1); SYNC_POST();

        // ---- T1 (buf1) ----
        // P5: stage A1(T2)
        read_a2<0, 0>(afl, ap1, lane);
        read_b4<0>(bf0, bp1, lane);
        if (wm == 0) read_b4<1>(bf1, bp1, lane);
        stage_half(Ag + H + s2, L + 8192, w);
        SYNC_PRE(); mfma8<0>(acc, afl, bf0); SYNC_POST();
        // P6: stage B0(T3)
        read_a2<2, 0>(afh, ap1, lane);
        if (wm == 1) read_b4<1>(bf1, bp1, lane);
        stage_half(Bg + s3, L + 49152, w);
        SYNC_PRE(); mfma8<1>(acc, afh, bf0); SYNC_POST();
        // P7: stage B1(T3)
        read_a2<0, 1>(afl, ap1, lane);
        if (wn == 0) read_a2<2, 1>(afh, ap1, lane);
        stage_half(Bg + H + s3, L + 57344, w);
        SYNC_PRE(); mfma8<0>(acc, afl, bf1); SYNC_POST();
        // P8: stage A0(T3); counted vmcnt -> T2 fully landed
        if (wn == 1) read_a2<2, 1>(afh, ap1, lane);
        stage_half(Ag + s3, L + 32768, w);
        VMCNT(6);
        SYNC_PRE(); mfma8<1>(acc, afh, bf1); SYNC_POST();
    }

    // ---- tail: T0=tile30 (buf0), T1=tile31 (buf1); only A1(T31) left to stage ----
    {
        // P1
        read_a2<0, 0>(afl, ap0, lane);
        read_b4<0>(bf0, bp0, lane);
        if (wm == 0) read_b4<1>(bf1, bp0, lane);
        stage_half(Ag + H + (size_t)31 * 128, L + 40960, w);   // A1(T31)
        SYNC_PRE(); mfma8<0>(acc, afl, bf0); SYNC_POST();
        // P2
        read_a2<2, 0>(afh, ap0, lane);
        if (wm == 1) read_b4<1>(bf1, bp0, lane);
        SYNC_PRE(); mfma8<1>(acc, afh, bf0); SYNC_POST();
        // P3
        read_a2<0, 1>(afl, ap0, lane);
        if (wn == 0) read_a2<2, 1>(afh, ap0, lane);
        SYNC_PRE(); mfma8<0>(acc, afl, bf1); SYNC_POST();
        // P4: drain everything (T31 fully landed)
        if (wn == 1) read_a2<2, 1>(afh, ap0, lane);
        VMCNT(0);
        SYNC_PRE(); mfma8<1>(acc, afh, bf1); SYNC_POST();
        // P5
        read_a2<0, 0>(afl, ap1, lane);
        read_b4<0>(bf0, bp1, lane);
        if (wm == 0) read_b4<1>(bf1, bp1, lane);
        SYNC_PRE(); mfma8<0>(acc, afl, bf0); SYNC_POST();
        // P6
        read_a2<2, 0>(afh, ap1, lane);
        if (wm == 1) read_b4<1>(bf1, bp1, lane);
        SYNC_PRE(); mfma8<1>(acc, afh, bf0); SYNC_POST();
        // P7
        read_a2<0, 1>(afl, ap1, lane);
        if (wn == 0) read_a2<2, 1>(afh, ap1, lane);
        SYNC_PRE(); mfma8<0>(acc, afl, bf1); SYNC_POST();
        // P8
        if (wn == 1) read_a2<2, 1>(afh, ap1, lane);
        SYNC_PRE(); mfma8<1>(acc, afh, bf1);
        __builtin_amdgcn_s_setprio(0);
    }

    // epilogue: C = acc * wscale / QSCALE
    int crow = m0 + wm * 64;
    int ccol = n0 + wn * 64;
    #pragma unroll
    for (int n = 0; n < 4; ++n) {
        int col = ccol + n * 16 + (lane & 15);
        float ws = wscale[col] * INV_QS;
        #pragma unroll
        for (int m = 0; m < 4; ++m) {
            int row0 = crow + m * 16 + (lane >> 4) * 4;
            #pragma unroll
            for (int r = 0; r < 4; ++r)
                C[(size_t)(row0 + r) * OUT_DIM + col] = (float)acc[m][n][r] * ws;
        }
    }
}

// ---------------- kernel 4: in-place LayerNorm over OUT + bias ----------------
__global__ __launch_bounds__(256) void ln_kernel(
    float* __restrict__ out, const float* __restrict__ bias)
{
    int row = blockIdx.x;
    int tid = threadIdx.x;
    float* p = out + (long long)row * OUT_DIM;

    float4 v[4];
    float sum = 0.f, sumsq = 0.f;
    #pragma unroll
    for (int q = 0; q < 4; ++q) {
        v[q] = *(const float4*)(p + (q * 256 + tid) * 4);
        sum   += v[q].x + v[q].y + v[q].z + v[q].w;
        sumsq += v[q].x*v[q].x + v[q].y*v[q].y + v[q].z*v[q].z + v[q].w*v[q].w;
    }
    #pragma unroll
    for (int off = 32; off > 0; off >>= 1) {
        sum   += __shfl_down(sum, off);
        sumsq += __shfl_down(sumsq, off);
    }
    __shared__ float ssum[4], ssq[4];
    if ((tid & 63) == 0) { ssum[tid >> 6] = sum; ssq[tid >> 6] = sumsq; }
    __syncthreads();
    sum   = ssum[0] + ssum[1] + ssum[2] + ssum[3];
    sumsq = ssq[0] + ssq[1] + ssq[2] + ssq[3];
    float mean = sum * (1.0f / OUT_DIM);
    float var  = sumsq * (1.0f / OUT_DIM) - mean * mean;
    float inv  = rsqrtf(var + EPS);

    #pragma unroll
    for (int q = 0; q < 4; ++q) {
        int c = (q * 256 + tid) * 4;
        float4 b = *(const float4*)(bias + c);
        float4 r;
        r.x = (v[q].x - mean) * inv + b.x;
        r.y = (v[q].y - mean) * inv + b.y;
        r.z = (v[q].z - mean) * inv + b.z;
        r.w = (v[q].w - mean) * inv + b.w;
        *(float4*)(p + c) = r;
    }
}

extern "C" void kernel_launch(void* const* d_in, const int* in_sizes, int n_in,
                              void* d_out, int out_size, void* d_ws, size_t ws_size,
                              hipStream_t stream) {
    const float* input   = (const float*)d_in[0];
    const int*   weight  = (const int*)d_in[1];
    const float* wscale  = (const float*)d_in[2];
    const float* factor  = (const float*)d_in[3];
    const float* bias    = (const float*)d_in[4];
    float* out = (float*)d_out;

    char* xq = (char*)d_ws;                                   // 32 MiB (8192x4096 i8)
    char* wq = (char*)d_ws + (size_t)N_ROWS * IN_DIM;         // 16 MiB (4096x4096 i8)

    {
        long long total = (long long)N_ROWS * IN_DIM / 16;    // 2M threads
        int blocks = (int)((total + 255) / 256);
        scale_quant_kernel<<<blocks, 256, 0, stream>>>(input, factor, xq);
    }
    {
        int total = OUT_DIM * (IN_DIM / 8);                   // 2M packed bytes
        unpack_kernel<<<(total + 255) / 256, 256, 0, stream>>>(weight, wq);
    }
    {
        int grid = (N_ROWS / 128) * (OUT_DIM / 128);          // 2048
        gemm_kernel<<<grid, 256, 0, stream>>>(xq, wq, wscale, out);
    }
    ln_kernel<<<N_ROWS, 256, 0, stream>>>(out, bias);
}

// Round 7
// 206.877 us; speedup vs baseline: 1.2044x; 1.2044x over previous
//
#include <hip/hip_runtime.h>
#include <hip/hip_bf16.h>
#include <stdint.h>

#define N_ROWS 8192
#define IN_DIM 4096
#define OUT_DIM 4096
#define EPS 1e-5f
#define QSCALE 16.0f
#define INV_QS 0.0625f

typedef __attribute__((ext_vector_type(4))) int i32x4;
typedef __attribute__((ext_vector_type(16))) char c8x16;
typedef __attribute__((ext_vector_type(8))) char c8x8;

typedef const __attribute__((address_space(1))) void gbl_void_t;
typedef __attribute__((address_space(3))) void lds_void_t;

__device__ __forceinline__ void gload_lds16(const void* g, void* l) {
    __builtin_amdgcn_global_load_lds((gbl_void_t*)g, (lds_void_t*)l, 16, 0, 0);
}

// ---------------- kernel 1: x_i8 = clamp(round(input * factor * 16), -127, 127) ----------------
__global__ __launch_bounds__(256) void scale_quant_kernel(
    const float* __restrict__ input, const float* __restrict__ factor,
    char* __restrict__ xq)
{
    long long idx = (long long)blockIdx.x * blockDim.x + threadIdx.x;
    long long base = idx * 16;
    if (base >= (long long)N_ROWS * IN_DIM) return;
    int col = (int)(base & (IN_DIM - 1));   // multiple of 16
    c8x16 r;
    #pragma unroll
    for (int q = 0; q < 4; ++q) {
        float4 a = *(const float4*)(input + base + q * 4);
        float4 f = *(const float4*)(factor + col + q * 4);
        float v[4] = {a.x*f.x, a.y*f.y, a.z*f.z, a.w*f.w};
        #pragma unroll
        for (int j = 0; j < 4; ++j) {
            int t = __float2int_rn(v[j] * QSCALE);
            t = t > 127 ? 127 : (t < -127 ? -127 : t);
            r[q * 4 + j] = (char)t;
        }
    }
    *(c8x16*)(xq + base) = r;
}

// ---------------- kernel 2: unpack packed ±1 weights to i8 ----------------
__global__ __launch_bounds__(256) void unpack_kernel(
    const int* __restrict__ wpacked, char* __restrict__ wq)
{
    int idx = blockIdx.x * blockDim.x + threadIdx.x;
    if (idx >= OUT_DIM * (IN_DIM / 8)) return;
    unsigned byte = (unsigned)wpacked[idx];
    c8x8 r;
    #pragma unroll
    for (int b = 0; b < 8; ++b)
        r[b] = (char)(1 - 2 * (int)((byte >> b) & 1u));   // bit0 -> +1, bit1 -> -1
    *(c8x8*)(wq + (long long)idx * 8) = r;
}

// ---------------- kernel 3: 256x256 8-phase i8 GEMM (r5 geometry) ----------------
// C[m][o] = (sum_k xq[m][k]*wq[o][k]) * wscale[o] / 16
// 512 thr = 8 waves (2M x 4N); wave tile 128x64; BK=128 i8; LDS 128KiB dbuf.
// r7 change vs r5: NO explicit lgkmcnt(0) drain before MFMA — the compiler's
// fine-grained counted lgkm waits let ds_reads drain UNDER the MFMA cluster.
// Safety: every LDS region has >=1 phase between last read and restage, and
// each read is consumed by an MFMA issued before the POST-barrier crossing.

template<int M0, int KS>
__device__ __forceinline__ void read_a4(i32x4 (&f)[4], const char* ap, int lane) {
    int rb = (lane & 15) << 7, g = lane >> 4, x = lane & 7;
    #pragma unroll
    for (int m = 0; m < 4; ++m)
        f[m] = *(const i32x4*)(ap + (M0 + m) * 2048 + rb + (((KS * 4 + g) ^ x) << 4));
}
template<int KS>
__device__ __forceinline__ void read_b4(i32x4 (&f)[4], const char* bp, int lane) {
    int rb = (lane & 15) << 7, g = lane >> 4, x = lane & 7;
    #pragma unroll
    for (int n = 0; n < 4; ++n)
        f[n] = *(const i32x4*)(bp + n * 2048 + rb + (((KS * 4 + g) ^ x) << 4));
}
template<int MQ>   // 0: acc rows 0..3, 1: acc rows 4..7
__device__ __forceinline__ void mfma16(i32x4 (&acc)[8][4], i32x4 (&a4)[4], i32x4 (&b4)[4]) {
    #pragma unroll
    for (int i = 0; i < 4; ++i)
        #pragma unroll
        for (int j = 0; j < 4; ++j)
            acc[MQ * 4 + i][j] = __builtin_amdgcn_mfma_i32_16x16x64_i8(
                a4[i], b4[j], acc[MQ * 4 + i][j], 0, 0, 0);
}

__device__ __forceinline__ void stage_half(const char* g, char* l, int w) {
    // wave w stages chunks 2w, 2w+1 (8 rows x 128B each) of one 128x128B half-tile
    gload_lds16(g + (size_t)(w * 16)     * IN_DIM, l + w * 2048);
    gload_lds16(g + (size_t)(w * 16 + 8) * IN_DIM, l + w * 2048 + 1024);
}

#define SYNC_PRE() do { __builtin_amdgcn_s_barrier(); \
    asm volatile("" ::: "memory"); \
    __builtin_amdgcn_s_setprio(1); } while(0)
#define SYNC_POST() do { __builtin_amdgcn_s_setprio(0); \
    asm volatile("" ::: "memory"); \
    __builtin_amdgcn_s_barrier(); } while(0)
#define VMCNT(n) asm volatile("s_waitcnt vmcnt(" #n ")" ::: "memory")

__global__ __launch_bounds__(512, 2) void gemm_kernel(
    const char* __restrict__ A, const char* __restrict__ B,
    const float* __restrict__ wscale, float* __restrict__ C)
{
    __shared__ char ldsb[131072];   // 128 KiB

    int nwg = gridDim.x;   // 512, divisible by 8
    int bid = blockIdx.x;
    int swz = (bid & 7) * (nwg >> 3) + (bid >> 3);   // bijective XCD swizzle
    int bn = swz & 15;
    int bm = swz >> 4;
    int m0 = bm * 256, n0 = bn * 256;

    int tid = threadIdx.x;
    int lane = tid & 63;
    int w = tid >> 6;
    int wm = w >> 2, wn = w & 3, wh = wn >> 1;

    // staging per-lane global base (inverse-swizzled source; swizzle key = row&7)
    int srow = lane >> 3, sslot = (lane & 7) ^ srow;
    const char* Ag = A + (size_t)(m0 + srow) * IN_DIM + sslot * 16;
    const char* Bg = B + (size_t)(n0 + srow) * IN_DIM + sslot * 16;
    const size_t H = (size_t)128 * IN_DIM;

    char* L = ldsb;
    // regions (bytes): buf0: A0=0 A1=16384 B0=32768 B1=49152; buf1: +65536
    const char* ap0 = ldsb + wm * 16384;
    const char* ap1 = ap0 + 65536;
    const char* bp0 = ldsb + 32768 + wh * 16384 + (wn & 1) * 8192;
    const char* bp1 = bp0 + 65536;

    i32x4 afl[4], afh[4], bf0[4], bf1[4];
    i32x4 acc[8][4] = {};

    // prologue: T0 -> buf0 (B0,B1,A0,A1); T1 -> buf1 (B0,B1,A0); 14 loads/wave
    stage_half(Bg,           L + 32768,  w);
    stage_half(Bg + H,       L + 49152,  w);
    stage_half(Ag,           L + 0,      w);
    stage_half(Ag + H,       L + 16384,  w);
    stage_half(Bg + 128,     L + 98304,  w);
    stage_half(Bg + H + 128, L + 114688, w);
    stage_half(Ag + 128,     L + 65536,  w);
    VMCNT(6);                     // T0's 8 loads landed
    __builtin_amdgcn_s_barrier();

    for (int it = 0; it < 15; ++it) {
        size_t s1 = (size_t)(2 * it + 1) * 128;
        size_t s2 = (size_t)(2 * it + 2) * 128;
        size_t s3 = (size_t)(2 * it + 3) * 128;

        // ---- T0 (buf0) ----
        // P1: stage A1(T1)
        read_a4<0, 0>(afl, ap0, lane);
        read_b4<0>(bf0, bp0, lane);
        if (wh == 0) read_b4<1>(bf1, bp0, lane);
        stage_half(Ag + H + s1, L + 81920, w);
        SYNC_PRE(); mfma16<0>(acc, afl, bf0); SYNC_POST();
        // P2: stage B0(T2)
        read_a4<4, 0>(afh, ap0, lane);
        if (wh == 1) read_b4<1>(bf1, bp0, lane);
        stage_half(Bg + s2, L + 32768, w);
        SYNC_PRE(); mfma16<1>(acc, afh, bf0); SYNC_POST();
        // P3: stage B1(T2)
        read_a4<0, 1>(afl, ap0, lane);
        if (wm == 0) read_a4<4, 1>(afh, ap0, lane);
        stage_half(Bg + H + s2, L + 49152, w);
        SYNC_PRE(); mfma16<0>(acc, afl, bf1); SYNC_POST();
        // P4: stage A0(T2); counted vmcnt -> T1 fully landed
        if (wm == 1) read_a4<4, 1>(afh, ap0, lane);
        stage_half(Ag + s2, L + 0, w);
        VMCNT(6);
        SYNC_PRE(); mfma16<1>(acc, afh, bf1); SYNC_POST();

        // ---- T1 (buf1) ----
        // P5: stage A1(T2)
        read_a4<0, 0>(afl, ap1, lane);
        read_b4<0>(bf0, bp1, lane);
        if (wh == 0) read_b4<1>(bf1, bp1, lane);
        stage_half(Ag + H + s2, L + 16384, w);
        SYNC_PRE(); mfma16<0>(acc, afl, bf0); SYNC_POST();
        // P6: stage B0(T3)
        read_a4<4, 0>(afh, ap1, lane);
        if (wh == 1) read_b4<1>(bf1, bp1, lane);
        stage_half(Bg + s3, L + 98304, w);
        SYNC_PRE(); mfma16<1>(acc, afh, bf0); SYNC_POST();
        // P7: stage B1(T3)
        read_a4<0, 1>(afl, ap1, lane);
        if (wm == 0) read_a4<4, 1>(afh, ap1, lane);
        stage_half(Bg + H + s3, L + 114688, w);
        SYNC_PRE(); mfma16<0>(acc, afl, bf1); SYNC_POST();
        // P8: stage A0(T3); counted vmcnt -> T2 fully landed
        if (wm == 1) read_a4<4, 1>(afh, ap1, lane);
        stage_half(Ag + s3, L + 65536, w);
        VMCNT(6);
        SYNC_PRE(); mfma16<1>(acc, afh, bf1); SYNC_POST();
    }

    // ---- tail: T0=tile30 (buf0), T1=tile31 (buf1); only A1(T31) left to stage ----
    {
        // P1
        read_a4<0, 0>(afl, ap0, lane);
        read_b4<0>(bf0, bp0, lane);
        if (wh == 0) read_b4<1>(bf1, bp0, lane);
        stage_half(Ag + H + (size_t)31 * 128, L + 81920, w);   // A1(T31)
        SYNC_PRE(); mfma16<0>(acc, afl, bf0); SYNC_POST();
        // P2
        read_a4<4, 0>(afh, ap0, lane);
        if (wh == 1) read_b4<1>(bf1, bp0, lane);
        SYNC_PRE(); mfma16<1>(acc, afh, bf0); SYNC_POST();
        // P3
        read_a4<0, 1>(afl, ap0, lane);
        if (wm == 0) read_a4<4, 1>(afh, ap0, lane);
        SYNC_PRE(); mfma16<0>(acc, afl, bf1); SYNC_POST();
        // P4: drain everything (T31 fully landed)
        if (wm == 1) read_a4<4, 1>(afh, ap0, lane);
        VMCNT(0);
        SYNC_PRE(); mfma16<1>(acc, afh, bf1); SYNC_POST();
        // P5
        read_a4<0, 0>(afl, ap1, lane);
        read_b4<0>(bf0, bp1, lane);
        if (wh == 0) read_b4<1>(bf1, bp1, lane);
        SYNC_PRE(); mfma16<0>(acc, afl, bf0); SYNC_POST();
        // P6
        read_a4<4, 0>(afh, ap1, lane);
        if (wh == 1) read_b4<1>(bf1, bp1, lane);
        SYNC_PRE(); mfma16<1>(acc, afh, bf0); SYNC_POST();
        // P7
        read_a4<0, 1>(afl, ap1, lane);
        if (wm == 0) read_a4<4, 1>(afh, ap1, lane);
        SYNC_PRE(); mfma16<0>(acc, afl, bf1); SYNC_POST();
        // P8
        if (wm == 1) read_a4<4, 1>(afh, ap1, lane);
        SYNC_PRE(); mfma16<1>(acc, afh, bf1);
        __builtin_amdgcn_s_setprio(0);
    }

    // epilogue: C = acc * wscale / QSCALE
    int crow = m0 + wm * 128;
    int ccol = n0 + wn * 64;
    #pragma unroll
    for (int n = 0; n < 4; ++n) {
        int col = ccol + n * 16 + (lane & 15);
        float ws = wscale[col] * INV_QS;
        #pragma unroll
        for (int m = 0; m < 8; ++m) {
            int row0 = crow + m * 16 + (lane >> 4) * 4;
            #pragma unroll
            for (int r = 0; r < 4; ++r)
                C[(size_t)(row0 + r) * OUT_DIM + col] = (float)acc[m][n][r] * ws;
        }
    }
}

// ---------------- kernel 4: in-place LayerNorm over OUT + bias ----------------
__global__ __launch_bounds__(256) void ln_kernel(
    float* __restrict__ out, const float* __restrict__ bias)
{
    int row = blockIdx.x;
    int tid = threadIdx.x;
    float* p = out + (long long)row * OUT_DIM;

    float4 v[4];
    float sum = 0.f, sumsq = 0.f;
    #pragma unroll
    for (int q = 0; q < 4; ++q) {
        v[q] = *(const float4*)(p + (q * 256 + tid) * 4);
        sum   += v[q].x + v[q].y + v[q].z + v[q].w;
        sumsq += v[q].x*v[q].x + v[q].y*v[q].y + v[q].z*v[q].z + v[q].w*v[q].w;
    }
    #pragma unroll
    for (int off = 32; off > 0; off >>= 1) {
        sum   += __shfl_down(sum, off);
        sumsq += __shfl_down(sumsq, off);
    }
    __shared__ float ssum[4], ssq[4];
    if ((tid & 63) == 0) { ssum[tid >> 6] = sum; ssq[tid >> 6] = sumsq; }
    __syncthreads();
    sum   = ssum[0] + ssum[1] + ssum[2] + ssum[3];
    sumsq = ssq[0] + ssq[1] + ssq[2] + ssq[3];
    float mean = sum * (1.0f / OUT_DIM);
    float var  = sumsq * (1.0f / OUT_DIM) - mean * mean;
    float inv  = rsqrtf(var + EPS);

    #pragma unroll
    for (int q = 0; q < 4; ++q) {
        int c = (q * 256 + tid) * 4;
        float4 b = *(const float4*)(bias + c);
        float4 r;
        r.x = (v[q].x - mean) * inv + b.x;
        r.y = (v[q].y - mean) * inv + b.y;
        r.z = (v[q].z - mean) * inv + b.z;
        r.w = (v[q].w - mean) * inv + b.w;
        *(float4*)(p + c) = r;
    }
}

extern "C" void kernel_launch(void* const* d_in, const int* in_sizes, int n_in,
                              void* d_out, int out_size, void* d_ws, size_t ws_size,
                              hipStream_t stream) {
    const float* input   = (const float*)d_in[0];
    const int*   weight  = (const int*)d_in[1];
    const float* wscale  = (const float*)d_in[2];
    const float* factor  = (const float*)d_in[3];
    const float* bias    = (const float*)d_in[4];
    float* out = (float*)d_out;

    char* xq = (char*)d_ws;                                   // 32 MiB (8192x4096 i8)
    char* wq = (char*)d_ws + (size_t)N_ROWS * IN_DIM;         // 16 MiB (4096x4096 i8)

    {
        long long total = (long long)N_ROWS * IN_DIM / 16;    // 2M threads
        int blocks = (int)((total + 255) / 256);
        scale_quant_kernel<<<blocks, 256, 0, stream>>>(input, factor, xq);
    }
    {
        int total = OUT_DIM * (IN_DIM / 8);                   // 2M packed bytes
        unpack_kernel<<<(total + 255) / 256, 256, 0, stream>>>(weight, wq);
    }
    {
        int grid = (N_ROWS / 256) * (OUT_DIM / 256);          // 512
        gemm_kernel<<<grid, 512, 0, stream>>>(xq, wq, wscale, out);
    }
    ln_kernel<<<N_ROWS, 256, 0, stream>>>(out, bias);
}